// Round 6
// baseline (600.793 us; speedup 1.0000x reference)
//
#include <hip/hip_runtime.h>
#include <math.h>

#define NN 200
#define ETOT 39800

typedef float float4v __attribute__((ext_vector_type(4)));
typedef short short8 __attribute__((ext_vector_type(8)));

__device__ __forceinline__ float sigf(float x) { return 1.0f / (1.0f + expf(-x)); }

__device__ __forceinline__ unsigned short f2b(float f) {
  unsigned u = __float_as_uint(f);
  u += 0x7fffu + ((u >> 16) & 1u);
  return (unsigned short)(u >> 16);
}
__device__ __forceinline__ float b2f16(unsigned short u) {
  return __uint_as_float(((unsigned)u) << 16);
}

// ---------------- device-scope grid barrier (counter pre-zeroed by k_prep) ----------------
__device__ __forceinline__ void gbar(unsigned* c, unsigned target) {
  __threadfence();                       // release my block's global writes (agent scope)
  __syncthreads();
  if (threadIdx.x == 0) {
    __hip_atomic_fetch_add(c, 1u, __ATOMIC_ACQ_REL, __HIP_MEMORY_SCOPE_AGENT);
    while (__hip_atomic_load(c, __ATOMIC_ACQUIRE, __HIP_MEMORY_SCOPE_AGENT) < target) {
      __builtin_amdgcn_s_sleep(2);
    }
  }
  __syncthreads();
  __threadfence();                       // acquire: invalidate stale cached lines
}

// ======================= prep: transposes + conversions + P/Q + barrier init =======================
__global__ __launch_bounds__(256) void k_prep(
    const float* __restrict__ w1, const float* __restrict__ w2, const float* __restrict__ w3,
    const float* __restrict__ wp2, const float* __restrict__ we2,
    const float* __restrict__ bbox, const float* __restrict__ dir,
    const float* __restrict__ we1, const float* __restrict__ be1,
    const float* __restrict__ roi, const float* __restrict__ wp1,
    unsigned short* __restrict__ w1T, unsigned short* __restrict__ w2T,
    unsigned short* __restrict__ w3T, unsigned short* __restrict__ WrT,
    unsigned short* __restrict__ we2T, unsigned short* __restrict__ roiB,
    float* __restrict__ P, float* __restrict__ Q, float* __restrict__ wp1T,
    unsigned* __restrict__ barr) {
  __shared__ float lds[64][65];
  const int b = blockIdx.x, tid = threadIdx.x;

  if (b < 352) {
    const float* Wf;
    unsigned short* Wt;
    int K, N, t;
    if (b < 256) { Wf = w1; Wt = w1T; K = 2048; N = 512; t = b; }
    else if (b < 288) { Wf = w2; Wt = w2T; K = 512; N = 256; t = b - 256; }
    else { Wf = w3; Wt = w3T; K = 256; N = 1024; t = b - 288; }
    const int K64 = K >> 6;
    const int kt = t % K64, nt = t / K64;
#pragma unroll 4
    for (int i = 0; i < 16; ++i) {
      int idx = tid + i * 256;
      int r = idx >> 6, c = idx & 63;
      lds[r][c] = Wf[(size_t)(kt * 64 + r) * N + nt * 64 + c];
    }
    __syncthreads();
#pragma unroll 4
    for (int i = 0; i < 16; ++i) {
      int idx = tid + i * 256;
      int r = idx >> 6, c = idx & 63;
      Wt[(size_t)(nt * 64 + r) * K + kt * 64 + c] = f2b(lds[c][r]);
    }
  } else if (b < 480) {
    int k = b - 352;
    int o = tid >> 6, l = tid & 63;
    const float* src = wp2 + (size_t)k * 4096;
    unsigned short* dst = WrT + (size_t)(k * 4 + o) * 1024;
    for (int i = l; i < 1024; i += 64) dst[i] = f2b(src[i * 4 + o]);
  } else if (b < 496) {
    int f = (b - 480) * 256 + tid;
    int c = f >> 6, k0 = (f & 63) * 4;
#pragma unroll
    for (int q = 0; q < 4; ++q)
      we2T[c * 256 + k0 + q] = f2b(we2[(k0 + q) * 64 + c]);
  } else if (b < 696) {
    int n = b - 496, c = tid;
    float a[8];
#pragma unroll
    for (int r = 0; r < 4; ++r) a[r] = bbox[n * 4 + r] * (1.0f / 1024.0f);
#pragma unroll
    for (int r = 0; r < 4; ++r) a[4 + r] = dir[n * 4 + r];
    float p = be1[c], q = 0.0f;
#pragma unroll
    for (int r = 0; r < 8; ++r) {
      p += a[r] * we1[r * 256 + c];
      q += a[r] * we1[(8 + r) * 256 + c];
    }
    P[n * 256 + c] = p;
    Q[n * 256 + c] = q;
  } else if (b < 896) {
    int n = b - 696;
    const float4v* R4 = (const float4v*)(roi + (size_t)n * 2048);
    unsigned long long* O = (unsigned long long*)(roiB + (size_t)n * 2048);
#pragma unroll
    for (int j = 0; j < 2; ++j) {
      int idx = tid + j * 256;
      float4v v = R4[idx];
      union { unsigned short us[4]; unsigned long long ll; } pk;
#pragma unroll
      for (int q = 0; q < 4; ++q) pk.us[q] = f2b(v[q]);
      O[idx] = pk.ll;
    }
  } else {
    if (tid < 128) {
      float4v v = {wp1[tid], wp1[128 + tid], wp1[256 + tid], wp1[384 + tid]};
      ((float4v*)wp1T)[tid] = v;
    } else if (tid < 136) {
      barr[tid - 128] = 0u;
    }
  }
}

// ======================= stage helpers for the mega-kernel =======================

// MFMA GEMM 16x16 tile, 4 waves split K, LDS reduce. A[208][K] bf16, B[N][K] bf16.
template <int KSTEPS, int RELU, int OUTF32, int HASBIAS>
__device__ __forceinline__ void gemm_tile(char* sm, int t,
                                          const unsigned short* __restrict__ A,
                                          const unsigned short* __restrict__ B,
                                          const float* __restrict__ bias,
                                          void* __restrict__ Cout, int N) {
  float (*red)[16][17] = (float (*)[16][17])sm;
  constexpr int K = KSTEPS * 128;
  const int tid = threadIdx.x, lane = tid & 63, wv = tid >> 6;
  const int m0 = (t % 13) * 16, n0 = (t / 13) * 16;
  const int mr = lane & 15, quad = lane >> 4;
  const unsigned short* Ap = A + (size_t)(m0 + mr) * K + wv * (KSTEPS * 32) + quad * 8;
  const unsigned short* Bp = B + (size_t)(n0 + mr) * K + wv * (KSTEPS * 32) + quad * 8;
  float4v acc = {0.f, 0.f, 0.f, 0.f};
#pragma unroll
  for (int s = 0; s < KSTEPS; ++s) {
    short8 af = *(const short8*)(Ap + s * 32);
    short8 bf = *(const short8*)(Bp + s * 32);
    acc = __builtin_amdgcn_mfma_f32_16x16x32_bf16(af, bf, acc, 0, 0, 0);
  }
  __syncthreads();   // guard sm reuse across tasks
#pragma unroll
  for (int r = 0; r < 4; ++r) red[wv][quad * 4 + r][mr] = acc[r];
  __syncthreads();
  const int row = tid >> 4, col = tid & 15;
  float v = red[0][row][col] + red[1][row][col] + red[2][row][col] + red[3][row][col];
  if (HASBIAS) v += bias[n0 + col];
  if (RELU) v = fmaxf(v, 0.f);
  if (OUTF32)
    ((float*)Cout)[(size_t)(m0 + row) * N + n0 + col] = v;
  else
    ((unsigned short*)Cout)[(size_t)(m0 + row) * N + n0 + col] = f2b(v);
}

// per-node: nce (out1), U, agg-init -> out0
__device__ __forceinline__ void nodevec_task(char* sm, int n,
                                             const unsigned short* __restrict__ xB,
                                             const float* __restrict__ wi, const float* __restrict__ bi,
                                             const float* __restrict__ root_w, const float* __restrict__ root_b,
                                             const float* __restrict__ bp2,
                                             float* __restrict__ out_nce, float* __restrict__ U,
                                             float* __restrict__ out0) {
  float (*part)[12] = (float (*)[12])sm;
  const int tid = threadIdx.x;
  float s[12] = {};
#pragma unroll
  for (int i = 0; i < 4; ++i) {
    int k = tid + i * 256;
    float xv = b2f16(xB[n * 1024 + k]);
    float4v wi4 = ((const float4v*)wi)[k];
    float4v rw4 = ((const float4v*)root_w)[k];
    float4v bp4 = ((const float4v*)bp2)[k];
#pragma unroll
    for (int c = 0; c < 4; ++c) {
      s[c] += xv * wi4[c];
      s[4 + c] += xv * rw4[c];
      s[8 + c] += xv * bp4[c];
    }
  }
  const int lane = tid & 63, wv = tid >> 6;
  __syncthreads();   // guard sm reuse
#pragma unroll
  for (int r = 0; r < 12; ++r) {
    float v = s[r];
#pragma unroll
    for (int off = 32; off > 0; off >>= 1) v += __shfl_down(v, off, 64);
    if (lane == 0) part[wv][r] = v;
  }
  __syncthreads();
  if (tid < 12) {
    float v = part[0][tid] + part[1][tid] + part[2][tid] + part[3][tid];
    int kind = tid >> 2, c = tid & 3;
    if (kind == 0) out_nce[n * 4 + c] = sigf(v + bi[c]);
    else if (kind == 1) out0[n * 4 + c] = v + root_b[c];
    else U[n * 4 + c] = v;
  }
}

// fused edge task: 64 edges. wp1s/bp1s already staged at sm[0..2560).
__device__ __forceinline__ void edge_task(char* sm, int t,
                                          const float* __restrict__ P, const float* __restrict__ Q,
                                          const unsigned short* __restrict__ we2T,
                                          const float* __restrict__ be2, const float* __restrict__ we3,
                                          const float* __restrict__ be3, const float* __restrict__ pri,
                                          const float* __restrict__ T, const float* __restrict__ U,
                                          float* __restrict__ out0, float* __restrict__ out_ea) {
  float4v* wp1s = (float4v*)sm;                 // [128]
  float* bp1s = (float*)(sm + 2048);            // [128]
  float4v (*Ts)[128] = (float4v (*)[128])(sm + 2560);  // [2][128]
  float (*Us)[4] = (float (*)[4])(sm + 6656);   // [2][4]
  int* src_s = (int*)(sm + 6688);               // [64]
  int* dst_s = (int*)(sm + 6944);               // [64]
  float (*ea_s)[4] = (float (*)[4])(sm + 7200); // [64][4]

  const int tid = threadIdx.x;
  const int e0 = t * 64;
  const int s_lo = e0 / 199;

  __syncthreads();   // guard: prior task's tail reads / wp1s staging ordering

  if (tid < 64) {
    int e = e0 + tid;
    int i = -1, j = 0;
    if (e < ETOT) {
      i = e / 199;
      int jj = e - i * 199;
      j = jj + (jj >= i ? 1 : 0);
    }
    src_s[tid] = i;
    dst_s[tid] = j;
  }
  {
    int row = tid >> 7, c = tid & 127;
    Ts[row][c] = ((const float4v*)T)[(s_lo + row) * 128 + c];  // row s_lo+1 may be pad (T has 208 rows)
  }
  if (tid < 8) {
    int s = min(s_lo + (tid >> 2), 199);
    Us[tid >> 2][tid & 3] = U[s * 4 + (tid & 3)];
  }
  __syncthreads();

  const int lane = tid & 63;
  const int wv = tid >> 6;
  const int m = lane & 15;
  const int quad = lane >> 4;
  const int eloc = wv * 16 + m;
  const int si = src_s[eloc];
  const int dj = dst_s[eloc];

  float4v acc[4];
#pragma unroll
  for (int ct = 0; ct < 4; ++ct) { acc[ct][0] = 0.f; acc[ct][1] = 0.f; acc[ct][2] = 0.f; acc[ct][3] = 0.f; }

  const short8* W8 = (const short8*)we2T;

  for (int ks = 0; ks < 8; ++ks) {
    union { short8 s; unsigned u[4]; } af;
    af.s = (short8)0;
    if (si >= 0) {
      const float4v* p4 = (const float4v*)(P + si * 256 + ks * 32 + quad * 8);
      const float4v* q4 = (const float4v*)(Q + dj * 256 + ks * 32 + quad * 8);
      float4v v0 = p4[0] + q4[0];
      float4v v1 = p4[1] + q4[1];
      af.u[0] = (unsigned)f2b(fmaxf(v0[0], 0.f)) | ((unsigned)f2b(fmaxf(v0[1], 0.f)) << 16);
      af.u[1] = (unsigned)f2b(fmaxf(v0[2], 0.f)) | ((unsigned)f2b(fmaxf(v0[3], 0.f)) << 16);
      af.u[2] = (unsigned)f2b(fmaxf(v1[0], 0.f)) | ((unsigned)f2b(fmaxf(v1[1], 0.f)) << 16);
      af.u[3] = (unsigned)f2b(fmaxf(v1[2], 0.f)) | ((unsigned)f2b(fmaxf(v1[3], 0.f)) << 16);
    }
#pragma unroll
    for (int ct = 0; ct < 4; ++ct) {
      short8 bf = W8[(ct * 16 + m) * 32 + ks * 4 + quad];
      acc[ct] = __builtin_amdgcn_mfma_f32_16x16x32_bf16(af.s, bf, acc[ct], 0, 0, 0);
    }
  }

  // eh2 = relu(acc + be2); ev = eh2 @ we3 (shfl-reduce over 64 cols)
  float ev[4][3];
#pragma unroll
  for (int r = 0; r < 4; ++r) { ev[r][0] = 0.f; ev[r][1] = 0.f; ev[r][2] = 0.f; }
#pragma unroll
  for (int ct = 0; ct < 4; ++ct) {
    const int col = ct * 16 + m;
    const float b2v = be2[col];
    const float w0 = we3[col * 3 + 0], w1v = we3[col * 3 + 1], w2v = we3[col * 3 + 2];
#pragma unroll
    for (int r = 0; r < 4; ++r) {
      float e2 = fmaxf(acc[ct][r] + b2v, 0.f);
      ev[r][0] += e2 * w0;
      ev[r][1] += e2 * w1v;
      ev[r][2] += e2 * w2v;
    }
  }
#pragma unroll
  for (int r = 0; r < 4; ++r)
#pragma unroll
    for (int p = 0; p < 3; ++p) {
      float v = ev[r][p];
      v += __shfl_xor(v, 1, 64);
      v += __shfl_xor(v, 2, 64);
      v += __shfl_xor(v, 4, 64);
      v += __shfl_xor(v, 8, 64);
      ev[r][p] = v;
    }
  if (m == 0) {
#pragma unroll
    for (int r = 0; r < 4; ++r) {
      int el = wv * 16 + quad * 4 + r;
      int ss = src_s[el], dd = dst_s[el];
      if (ss >= 0) {
        float4v o;
        o[0] = sigf(ev[r][0] + be3[0]);
        o[1] = sigf(ev[r][1] + be3[1]);
        o[2] = sigf(ev[r][2] + be3[2]);
        o[3] = (pri[ss] > pri[dd]) ? 1.0f : 0.0f;
        *(float4v*)&ea_s[el][0] = o;
        *(float4v*)(out_ea + (size_t)(e0 + el) * 4) = o;
      }
    }
  }
  __syncthreads();

  // tail: h = relu(bp1 + ea@wp1) [128]; msg = h @ T[src]; 4 threads/edge, all LDS
  const int ee = tid >> 2, pp = tid & 3;
  const int s2 = src_s[ee], d2 = dst_s[ee];
  float4v pm = {0.f, 0.f, 0.f, 0.f};
  if (s2 >= 0) {
    const int srow = s2 - s_lo;
    const float c0 = ea_s[ee][0], c1 = ea_s[ee][1], c2 = ea_s[ee][2], c3 = ea_s[ee][3];
#pragma unroll 8
    for (int tt = pp; tt < 128; tt += 4) {
      float4v w4 = wp1s[tt];
      float hv = bp1s[tt] + c0 * w4[0] + c1 * w4[1] + c2 * w4[2] + c3 * w4[3];
      hv = fmaxf(hv, 0.f);
      pm += hv * Ts[srow][tt];
    }
  }
#pragma unroll
  for (int o = 0; o < 4; ++o) {
    float v = pm[o];
    v += __shfl_xor(v, 1, 64);
    v += __shfl_xor(v, 2, 64);
    pm[o] = v;
  }
  if (s2 >= 0) atomicAdd(&out0[d2 * 4 + pp], Us[s2 - s_lo][pp] + pm[pp]);
}

// ======================= mega-kernel: all stages, 4 grid barriers =======================
__global__ __launch_bounds__(256, 2) void mega(
    const unsigned short* roiB, const unsigned short* w1T, const float* b1, unsigned short* h1,
    const unsigned short* w2T, const float* b2, unsigned short* h2,
    const unsigned short* w3T, const float* b3, unsigned short* xB,
    const unsigned short* WrT, float* Tm,
    const float* wi, const float* bi, const float* rootw, const float* rootb, const float* bp2,
    float* out1, float* Um, float* out0,
    const float* Pm, const float* Qm, const unsigned short* we2T,
    const float* be2, const float* we3, const float* be3,
    const float* wp1T, const float* bp1, const float* pri,
    float* out2, unsigned* barr) {
  __shared__ __align__(16) char sm[8448];
  const int tid = threadIdx.x;
  const unsigned NB = gridDim.x;

  // stage 1: h1 = relu(roiB @ w1T + b1)   [208x512, K=2048] — 416 tiles
  for (unsigned t = blockIdx.x; t < 416; t += NB)
    gemm_tile<16, 1, 0, 1>(sm, t, roiB, w1T, b1, h1, 512);
  gbar(barr + 0, NB);

  // stage 2: h2 = relu(h1 @ w2T + b2)     [208x256, K=512] — 208 tiles
  for (unsigned t = blockIdx.x; t < 208; t += NB)
    gemm_tile<4, 1, 0, 1>(sm, t, h1, w2T, b2, h2, 256);
  gbar(barr + 1, NB);

  // stage 3: xB = h2 @ w3T + b3           [208x1024, K=256] — 832 tiles
  for (unsigned t = blockIdx.x; t < 832; t += NB)
    gemm_tile<2, 0, 0, 1>(sm, t, h2, w3T, b3, xB, 1024);
  gbar(barr + 2, NB);

  // stage 4: Tm = xB @ WrT [208x512, K=1024] (416 tiles)  ||  nodevec (200 tasks)
  for (unsigned t = blockIdx.x; t < 616; t += NB) {
    if (t < 416) gemm_tile<8, 0, 1, 0>(sm, t, xB, WrT, nullptr, Tm, 512);
    else nodevec_task(sm, t - 416, xB, wi, bi, rootw, rootb, bp2, out1, Um, out0);
  }
  gbar(barr + 3, NB);

  // stage 5: edges — preload wp1/bp1 once, then 622 tasks
  {
    float4v* wp1s = (float4v*)sm;
    float* bp1s = (float*)(sm + 2048);
    if (tid < 128) {
      wp1s[tid] = ((const float4v*)wp1T)[tid];
      bp1s[tid] = bp1[tid];
    }
  }
  for (unsigned t = blockIdx.x; t < 622; t += NB)
    edge_task(sm, t, Pm, Qm, we2T, be2, we3, be3, pri, Tm, Um, out0, out2);
}

extern "C" void kernel_launch(void* const* d_in, const int* in_sizes, int n_in,
                              void* d_out, int out_size, void* d_ws, size_t ws_size,
                              hipStream_t stream) {
  (void)in_sizes; (void)n_in; (void)out_size; (void)ws_size;
  const float* roi   = (const float*)d_in[0];
  const float* bbox  = (const float*)d_in[1];
  const float* dir   = (const float*)d_in[2];
  const float* pri   = (const float*)d_in[3];
  const float* w1    = (const float*)d_in[4];
  const float* b1    = (const float*)d_in[5];
  const float* w2    = (const float*)d_in[6];
  const float* b2    = (const float*)d_in[7];
  const float* w3    = (const float*)d_in[8];
  const float* b3    = (const float*)d_in[9];
  const float* wi    = (const float*)d_in[10];
  const float* bi    = (const float*)d_in[11];
  const float* we1   = (const float*)d_in[12];
  const float* be1   = (const float*)d_in[13];
  const float* we2   = (const float*)d_in[14];
  const float* be2   = (const float*)d_in[15];
  const float* we3   = (const float*)d_in[16];
  const float* be3   = (const float*)d_in[17];
  const float* wp1   = (const float*)d_in[18];
  const float* bp1   = (const float*)d_in[19];
  const float* wp2   = (const float*)d_in[20];
  const float* bp2   = (const float*)d_in[21];
  const float* rootw = (const float*)d_in[22];
  const float* rootb = (const float*)d_in[23];

  float* out0 = (float*)d_out;        // next_actions [200,4]
  float* out1 = out0 + 800;           // node_concepts_explicit[0] [200,4]
  float* out2 = out0 + 1600;          // edge_attributes[0] [39800,4]

  // ---- workspace layout ----
  unsigned short* us = (unsigned short*)d_ws;
  unsigned short* w1T  = us;                 // [512][2048]
  unsigned short* w2T  = us + 1048576;       // [256][512]
  unsigned short* w3T  = us + 1179648;       // [1024][256]
  unsigned short* WrT  = us + 1441792;       // [512][1024]
  unsigned short* we2T = us + 1966080;       // [64][256]
  unsigned short* roiB = us + 1982464;       // [208][2048]
  unsigned short* h1   = us + 2408448;       // [208][512]
  unsigned short* h2   = us + 2514944;       // [208][256]
  unsigned short* xB   = us + 2568192;       // [208][1024]
  float* fb   = (float*)(us + 2781184);
  float* Tm   = fb;                          // [208][512]
  float* Pm   = fb + 106496;                 // [200][256]
  float* Qm   = fb + 157696;                 // [200][256]
  float* Um   = fb + 208896;                 // [200][4]
  float* wp1T = fb + 209696;                 // float4[128]
  unsigned* barr = (unsigned*)(fb + 210208); // [8] grid-barrier counters

  // launch 1: prep (transposes, conversions, P/Q, barrier init)
  k_prep<<<897, 256, 0, stream>>>(w1, w2, w3, wp2, we2, bbox, dir, we1, be1, roi, wp1,
                                  w1T, w2T, w3T, WrT, we2T, roiB, Pm, Qm, wp1T, barr);

  // launch 2: everything else (persistent, 2 blocks/CU guaranteed resident)
  mega<<<512, 256, 0, stream>>>(roiB, w1T, b1, h1, w2T, b2, h2, w3T, b3, xB, WrT, Tm,
                                wi, bi, rootw, rootb, bp2, out1, Um, out0,
                                Pm, Qm, we2T, be2, we3, be3, wp1T, bp1, pri, out2, barr);
}

// Round 7
// 249.707 us; speedup vs baseline: 2.4060x; 2.4060x over previous
//
#include <hip/hip_runtime.h>
#include <math.h>

#define NN 200
#define ETOT 39800

typedef float float4v __attribute__((ext_vector_type(4)));
typedef short short8 __attribute__((ext_vector_type(8)));

__device__ __forceinline__ float sigf(float x) { return 1.0f / (1.0f + expf(-x)); }

__device__ __forceinline__ unsigned short f2b(float f) {
  unsigned u = __float_as_uint(f);
  u += 0x7fffu + ((u >> 16) & 1u);
  return (unsigned short)(u >> 16);
}
__device__ __forceinline__ float b2f16(unsigned short u) {
  return __uint_as_float(((unsigned)u) << 16);
}

// ======================= prep: transposes + conversions + P/Q =======================
// blocks [0,352): weight transposes  [352,480): WrT  [480,496): we2T
// [496,696): P/Q  [696,896): roi->bf16  896: wp1T
__global__ __launch_bounds__(256) void k_prep(
    const float* __restrict__ w1, const float* __restrict__ w2, const float* __restrict__ w3,
    const float* __restrict__ wp2, const float* __restrict__ we2,
    const float* __restrict__ bbox, const float* __restrict__ dir,
    const float* __restrict__ we1, const float* __restrict__ be1,
    const float* __restrict__ roi, const float* __restrict__ wp1,
    unsigned short* __restrict__ w1T, unsigned short* __restrict__ w2T,
    unsigned short* __restrict__ w3T, unsigned short* __restrict__ WrT,
    unsigned short* __restrict__ we2T, unsigned short* __restrict__ roiB,
    float* __restrict__ P, float* __restrict__ Q, float* __restrict__ wp1T) {
  __shared__ float lds[64][65];
  const int b = blockIdx.x, tid = threadIdx.x;

  if (b < 352) {
    const float* Wf;
    unsigned short* Wt;
    int K, N, t;
    if (b < 256) { Wf = w1; Wt = w1T; K = 2048; N = 512; t = b; }
    else if (b < 288) { Wf = w2; Wt = w2T; K = 512; N = 256; t = b - 256; }
    else { Wf = w3; Wt = w3T; K = 256; N = 1024; t = b - 288; }
    const int K64 = K >> 6;
    const int kt = t % K64, nt = t / K64;
#pragma unroll 4
    for (int i = 0; i < 16; ++i) {
      int idx = tid + i * 256;
      int r = idx >> 6, c = idx & 63;
      lds[r][c] = Wf[(size_t)(kt * 64 + r) * N + nt * 64 + c];
    }
    __syncthreads();
#pragma unroll 4
    for (int i = 0; i < 16; ++i) {
      int idx = tid + i * 256;
      int r = idx >> 6, c = idx & 63;
      Wt[(size_t)(nt * 64 + r) * K + kt * 64 + c] = f2b(lds[c][r]);
    }
  } else if (b < 480) {
    int k = b - 352;
    int o = tid >> 6, l = tid & 63;
    const float* src = wp2 + (size_t)k * 4096;
    unsigned short* dst = WrT + (size_t)(k * 4 + o) * 1024;
    for (int i = l; i < 1024; i += 64) dst[i] = f2b(src[i * 4 + o]);
  } else if (b < 496) {
    int f = (b - 480) * 256 + tid;
    int c = f >> 6, k0 = (f & 63) * 4;
#pragma unroll
    for (int q = 0; q < 4; ++q)
      we2T[c * 256 + k0 + q] = f2b(we2[(k0 + q) * 64 + c]);
  } else if (b < 696) {
    int n = b - 496, c = tid;
    float a[8];
#pragma unroll
    for (int r = 0; r < 4; ++r) a[r] = bbox[n * 4 + r] * (1.0f / 1024.0f);
#pragma unroll
    for (int r = 0; r < 4; ++r) a[4 + r] = dir[n * 4 + r];
    float p = be1[c], q = 0.0f;
#pragma unroll
    for (int r = 0; r < 8; ++r) {
      p += a[r] * we1[r * 256 + c];
      q += a[r] * we1[(8 + r) * 256 + c];
    }
    P[n * 256 + c] = p;
    Q[n * 256 + c] = q;
  } else if (b < 896) {
    int n = b - 696;
    const float4v* R4 = (const float4v*)(roi + (size_t)n * 2048);
    unsigned long long* O = (unsigned long long*)(roiB + (size_t)n * 2048);
#pragma unroll
    for (int j = 0; j < 2; ++j) {
      int idx = tid + j * 256;
      float4v v = R4[idx];
      union { unsigned short us[4]; unsigned long long ll; } pk;
#pragma unroll
      for (int q = 0; q < 4; ++q) pk.us[q] = f2b(v[q]);
      O[idx] = pk.ll;
    }
  } else {
    if (tid < 128) {
      float4v v = {wp1[tid], wp1[128 + tid], wp1[256 + tid], wp1[384 + tid]};
      ((float4v*)wp1T)[tid] = v;
    }
  }
}

// ======================= fused node chain: 1 block = 16 rows, all layers =======================
// h1 = relu(roi@w1T+b1); h2 = relu(h1@w2T+b2); x = h2@w3T+b3 (LDS only);
// Tm = x@WrT (f32, global); nodevec: nce->out1, agg-init->out0, U->Um.
// 13 blocks x 1024 threads (16 waves). Weights streamed from L2 (~3.75 MB/block).
__global__ __launch_bounds__(1024, 1) void k_chain(
    const unsigned short* __restrict__ roiB,
    const unsigned short* __restrict__ w1T, const float* __restrict__ b1,
    const unsigned short* __restrict__ w2T, const float* __restrict__ b2,
    const unsigned short* __restrict__ w3T, const float* __restrict__ b3,
    const unsigned short* __restrict__ WrT,
    const float* __restrict__ wi, const float* __restrict__ bi,
    const float* __restrict__ rootw, const float* __restrict__ rootb,
    const float* __restrict__ bp2,
    float* __restrict__ out1, float* __restrict__ Um, float* __restrict__ out0,
    float* __restrict__ Tm) {
  // LDS overlay (49,664 B):
  //   bufA = [0,33024)        roi K-half   [16][1032]     (live: stage A)
  //   h1s  = [33024,49664)    [16][520]                   (live: A epi -> B)
  //   h2s  = [0,8448)         [16][264]                   (live: B epi -> C)
  //   xs   = [8448,41472)     [16][1032]                  (live: C epi -> D,E)
  __shared__ __align__(16) char sm[49664];
  unsigned short* bufA = (unsigned short*)sm;
  unsigned short* h1s  = (unsigned short*)(sm + 33024);
  unsigned short* h2s  = (unsigned short*)sm;
  unsigned short* xs   = (unsigned short*)(sm + 8448);

  const int tid = threadIdx.x;
  const int lane = tid & 63, wv = tid >> 6;     // 16 waves
  const int m0 = blockIdx.x * 16;
  const int mr = lane & 15, quad = lane >> 4;

  // ---------- stage A: h1[16x512], K=2048 in two LDS halves ----------
  float4v accA[2];
#pragma unroll
  for (int ct = 0; ct < 2; ++ct) { accA[ct][0]=0.f; accA[ct][1]=0.f; accA[ct][2]=0.f; accA[ct][3]=0.f; }
  for (int h = 0; h < 2; ++h) {
    __syncthreads();
    for (int i = tid; i < 2048; i += 1024) {      // 16 rows x 128 short8
      int row = i >> 7, off = (i & 127) * 8;
      *(short8*)(bufA + row * 1032 + off) =
          *(const short8*)(roiB + (size_t)(m0 + row) * 2048 + h * 1024 + off);
    }
    __syncthreads();
    for (int ks = 0; ks < 32; ++ks) {
      short8 af = *(const short8*)(bufA + mr * 1032 + ks * 32 + quad * 8);
#pragma unroll
      for (int ct = 0; ct < 2; ++ct) {
        int n = wv * 32 + ct * 16 + mr;
        short8 bf = *(const short8*)(w1T + (size_t)n * 2048 + h * 1024 + ks * 32 + quad * 8);
        accA[ct] = __builtin_amdgcn_mfma_f32_16x16x32_bf16(af, bf, accA[ct], 0, 0, 0);
      }
    }
  }
#pragma unroll
  for (int ct = 0; ct < 2; ++ct) {
    int col = wv * 32 + ct * 16 + mr;
    float bv = b1[col];
#pragma unroll
    for (int r = 0; r < 4; ++r)
      h1s[(quad * 4 + r) * 520 + col] = f2b(fmaxf(accA[ct][r] + bv, 0.f));
  }
  __syncthreads();

  // ---------- stage B: h2[16x256], K=512 ----------
  float4v accB = {0.f, 0.f, 0.f, 0.f};
  {
    int n = wv * 16 + mr;
    for (int ks = 0; ks < 16; ++ks) {
      short8 af = *(const short8*)(h1s + mr * 520 + ks * 32 + quad * 8);
      short8 bf = *(const short8*)(w2T + (size_t)n * 512 + ks * 32 + quad * 8);
      accB = __builtin_amdgcn_mfma_f32_16x16x32_bf16(af, bf, accB, 0, 0, 0);
    }
    int col = wv * 16 + mr;
    float bv = b2[col];
#pragma unroll
    for (int r = 0; r < 4; ++r)
      h2s[(quad * 4 + r) * 264 + col] = f2b(fmaxf(accB[r] + bv, 0.f));
  }
  __syncthreads();

  // ---------- stage C: x[16x1024], K=256 (LDS only) ----------
  float4v accC[4];
#pragma unroll
  for (int ct = 0; ct < 4; ++ct) { accC[ct][0]=0.f; accC[ct][1]=0.f; accC[ct][2]=0.f; accC[ct][3]=0.f; }
  for (int ks = 0; ks < 8; ++ks) {
    short8 af = *(const short8*)(h2s + mr * 264 + ks * 32 + quad * 8);
#pragma unroll
    for (int ct = 0; ct < 4; ++ct) {
      int n = wv * 64 + ct * 16 + mr;
      short8 bf = *(const short8*)(w3T + (size_t)n * 256 + ks * 32 + quad * 8);
      accC[ct] = __builtin_amdgcn_mfma_f32_16x16x32_bf16(af, bf, accC[ct], 0, 0, 0);
    }
  }
#pragma unroll
  for (int ct = 0; ct < 4; ++ct) {
    int col = wv * 64 + ct * 16 + mr;
    float bv = b3[col];
#pragma unroll
    for (int r = 0; r < 4; ++r)
      xs[(quad * 4 + r) * 1032 + col] = f2b(accC[ct][r] + bv);
  }
  __syncthreads();

  // ---------- stage D: Tm[16x512] = x @ WrT, K=1024, f32 out ----------
  float4v accD[2];
#pragma unroll
  for (int ct = 0; ct < 2; ++ct) { accD[ct][0]=0.f; accD[ct][1]=0.f; accD[ct][2]=0.f; accD[ct][3]=0.f; }
  for (int ks = 0; ks < 32; ++ks) {
    short8 af = *(const short8*)(xs + mr * 1032 + ks * 32 + quad * 8);
#pragma unroll
    for (int ct = 0; ct < 2; ++ct) {
      int n = wv * 32 + ct * 16 + mr;
      short8 bf = *(const short8*)(WrT + (size_t)n * 1024 + ks * 32 + quad * 8);
      accD[ct] = __builtin_amdgcn_mfma_f32_16x16x32_bf16(af, bf, accD[ct], 0, 0, 0);
    }
  }
#pragma unroll
  for (int ct = 0; ct < 2; ++ct) {
    int col = wv * 32 + ct * 16 + mr;
#pragma unroll
    for (int r = 0; r < 4; ++r)
      Tm[(size_t)(m0 + quad * 4 + r) * 512 + col] = accD[ct][r];
  }

  // ---------- stage E: nodevec for the 16 local rows (reads xs, no sync needed) ----------
  {
    int n = m0 + wv;
    if (n < NN) {
      float s[12] = {};
#pragma unroll 4
      for (int i = 0; i < 16; ++i) {
        int k = lane + i * 64;
        float xv = b2f16(xs[wv * 1032 + k]);
        float4v wi4 = ((const float4v*)wi)[k];
        float4v rw4 = ((const float4v*)rootw)[k];
        float4v bp4 = ((const float4v*)bp2)[k];
#pragma unroll
        for (int c = 0; c < 4; ++c) {
          s[c] += xv * wi4[c];
          s[4 + c] += xv * rw4[c];
          s[8 + c] += xv * bp4[c];
        }
      }
#pragma unroll
      for (int r = 0; r < 12; ++r) {
#pragma unroll
        for (int off = 32; off > 0; off >>= 1) s[r] += __shfl_down(s[r], off, 64);
      }
      if (lane == 0) {
#pragma unroll
        for (int c = 0; c < 4; ++c) {
          out1[n * 4 + c] = sigf(s[c] + bi[c]);
          out0[n * 4 + c] = s[4 + c] + rootb[c];
          Um[n * 4 + c] = s[8 + c];
        }
      }
    }
  }
}

// ======================= fused edge kernel (MFMA + LDS-staged tail) =======================
__global__ __launch_bounds__(256) void k_edge(
    const float* __restrict__ P, const float* __restrict__ Q,
    const unsigned short* __restrict__ we2T,
    const float* __restrict__ be2, const float* __restrict__ we3, const float* __restrict__ be3,
    const float* __restrict__ wp1T, const float* __restrict__ bp1,
    const float* __restrict__ pri,
    const float* __restrict__ T, const float* __restrict__ U,
    float* __restrict__ out0, float* __restrict__ out_ea) {
  __shared__ int src_s[64], dst_s[64];
  __shared__ float ea_s[64][4];
  __shared__ float4v wp1s[128];
  __shared__ float bp1s[128];
  __shared__ float4v Ts[2][128];
  __shared__ float Us[2][4];

  const int tid = threadIdx.x;
  const int e0 = blockIdx.x * 64;
  const int s_lo = e0 / 199;

  if (tid < 64) {
    int e = e0 + tid;
    int i = -1, j = 0;
    if (e < ETOT) {
      i = e / 199;
      int jj = e - i * 199;
      j = jj + (jj >= i ? 1 : 0);
    }
    src_s[tid] = i;
    dst_s[tid] = j;
  }
  if (tid < 128) {
    wp1s[tid] = ((const float4v*)wp1T)[tid];
    bp1s[tid] = bp1[tid];
  }
  {
    int row = tid >> 7, c = tid & 127;
    Ts[row][c] = ((const float4v*)T)[(s_lo + row) * 128 + c];  // row s_lo+1 may be pad (T has 208 rows)
  }
  if (tid < 8) {
    int s = min(s_lo + (tid >> 2), 199);
    Us[tid >> 2][tid & 3] = U[s * 4 + (tid & 3)];
  }
  __syncthreads();

  const int lane = tid & 63;
  const int wv = tid >> 6;
  const int m = lane & 15;
  const int quad = lane >> 4;
  const int eloc = wv * 16 + m;
  const int si = src_s[eloc];
  const int dj = dst_s[eloc];

  float4v acc[4];
#pragma unroll
  for (int ct = 0; ct < 4; ++ct) { acc[ct][0] = 0.f; acc[ct][1] = 0.f; acc[ct][2] = 0.f; acc[ct][3] = 0.f; }

  const short8* W8 = (const short8*)we2T;

  for (int ks = 0; ks < 8; ++ks) {
    union { short8 s; unsigned u[4]; } af;
    af.s = (short8)0;
    if (si >= 0) {
      const float4v* p4 = (const float4v*)(P + si * 256 + ks * 32 + quad * 8);
      const float4v* q4 = (const float4v*)(Q + dj * 256 + ks * 32 + quad * 8);
      float4v v0 = p4[0] + q4[0];
      float4v v1 = p4[1] + q4[1];
      af.u[0] = (unsigned)f2b(fmaxf(v0[0], 0.f)) | ((unsigned)f2b(fmaxf(v0[1], 0.f)) << 16);
      af.u[1] = (unsigned)f2b(fmaxf(v0[2], 0.f)) | ((unsigned)f2b(fmaxf(v0[3], 0.f)) << 16);
      af.u[2] = (unsigned)f2b(fmaxf(v1[0], 0.f)) | ((unsigned)f2b(fmaxf(v1[1], 0.f)) << 16);
      af.u[3] = (unsigned)f2b(fmaxf(v1[2], 0.f)) | ((unsigned)f2b(fmaxf(v1[3], 0.f)) << 16);
    }
#pragma unroll
    for (int ct = 0; ct < 4; ++ct) {
      short8 bf = W8[(ct * 16 + m) * 32 + ks * 4 + quad];
      acc[ct] = __builtin_amdgcn_mfma_f32_16x16x32_bf16(af.s, bf, acc[ct], 0, 0, 0);
    }
  }

  float ev[4][3];
#pragma unroll
  for (int r = 0; r < 4; ++r) { ev[r][0] = 0.f; ev[r][1] = 0.f; ev[r][2] = 0.f; }
#pragma unroll
  for (int ct = 0; ct < 4; ++ct) {
    const int col = ct * 16 + m;
    const float b2v = be2[col];
    const float w0 = we3[col * 3 + 0], w1v = we3[col * 3 + 1], w2v = we3[col * 3 + 2];
#pragma unroll
    for (int r = 0; r < 4; ++r) {
      float e2 = fmaxf(acc[ct][r] + b2v, 0.f);
      ev[r][0] += e2 * w0;
      ev[r][1] += e2 * w1v;
      ev[r][2] += e2 * w2v;
    }
  }
#pragma unroll
  for (int r = 0; r < 4; ++r)
#pragma unroll
    for (int p = 0; p < 3; ++p) {
      float v = ev[r][p];
      v += __shfl_xor(v, 1, 64);
      v += __shfl_xor(v, 2, 64);
      v += __shfl_xor(v, 4, 64);
      v += __shfl_xor(v, 8, 64);
      ev[r][p] = v;
    }
  if (m == 0) {
#pragma unroll
    for (int r = 0; r < 4; ++r) {
      int el = wv * 16 + quad * 4 + r;
      int ss = src_s[el], dd = dst_s[el];
      if (ss >= 0) {
        float4v o;
        o[0] = sigf(ev[r][0] + be3[0]);
        o[1] = sigf(ev[r][1] + be3[1]);
        o[2] = sigf(ev[r][2] + be3[2]);
        o[3] = (pri[ss] > pri[dd]) ? 1.0f : 0.0f;
        *(float4v*)&ea_s[el][0] = o;
        *(float4v*)(out_ea + (size_t)(e0 + el) * 4) = o;
      }
    }
  }
  __syncthreads();

  const int ee = tid >> 2, pp = tid & 3;
  const int s2 = src_s[ee], d2 = dst_s[ee];
  float4v pm = {0.f, 0.f, 0.f, 0.f};
  if (s2 >= 0) {
    const int srow = s2 - s_lo;
    const float c0 = ea_s[ee][0], c1 = ea_s[ee][1], c2 = ea_s[ee][2], c3 = ea_s[ee][3];
#pragma unroll 8
    for (int tt = pp; tt < 128; tt += 4) {
      float4v w4 = wp1s[tt];
      float hv = bp1s[tt] + c0 * w4[0] + c1 * w4[1] + c2 * w4[2] + c3 * w4[3];
      hv = fmaxf(hv, 0.f);
      pm += hv * Ts[srow][tt];
    }
  }
#pragma unroll
  for (int o = 0; o < 4; ++o) {
    float v = pm[o];
    v += __shfl_xor(v, 1, 64);
    v += __shfl_xor(v, 2, 64);
    pm[o] = v;
  }
  if (s2 >= 0) atomicAdd(&out0[d2 * 4 + pp], Us[s2 - s_lo][pp] + pm[pp]);
}

extern "C" void kernel_launch(void* const* d_in, const int* in_sizes, int n_in,
                              void* d_out, int out_size, void* d_ws, size_t ws_size,
                              hipStream_t stream) {
  (void)in_sizes; (void)n_in; (void)out_size; (void)ws_size;
  const float* roi   = (const float*)d_in[0];
  const float* bbox  = (const float*)d_in[1];
  const float* dir   = (const float*)d_in[2];
  const float* pri   = (const float*)d_in[3];
  const float* w1    = (const float*)d_in[4];
  const float* b1    = (const float*)d_in[5];
  const float* w2    = (const float*)d_in[6];
  const float* b2    = (const float*)d_in[7];
  const float* w3    = (const float*)d_in[8];
  const float* b3    = (const float*)d_in[9];
  const float* wi    = (const float*)d_in[10];
  const float* bi    = (const float*)d_in[11];
  const float* we1   = (const float*)d_in[12];
  const float* be1   = (const float*)d_in[13];
  const float* we2   = (const float*)d_in[14];
  const float* be2   = (const float*)d_in[15];
  const float* we3   = (const float*)d_in[16];
  const float* be3   = (const float*)d_in[17];
  const float* wp1   = (const float*)d_in[18];
  const float* bp1   = (const float*)d_in[19];
  const float* wp2   = (const float*)d_in[20];
  const float* bp2   = (const float*)d_in[21];
  const float* rootw = (const float*)d_in[22];
  const float* rootb = (const float*)d_in[23];

  float* out0 = (float*)d_out;        // next_actions [200,4]
  float* out1 = out0 + 800;           // node_concepts_explicit[0] [200,4]
  float* out2 = out0 + 1600;          // edge_attributes[0] [39800,4]

  // ---- workspace layout (same offsets as round 5) ----
  unsigned short* us = (unsigned short*)d_ws;
  unsigned short* w1T  = us;                 // [512][2048]
  unsigned short* w2T  = us + 1048576;       // [256][512]
  unsigned short* w3T  = us + 1179648;       // [1024][256]
  unsigned short* WrT  = us + 1441792;       // [512][1024]
  unsigned short* we2T = us + 1966080;       // [64][256]
  unsigned short* roiB = us + 1982464;       // [208][2048]
  float* fb   = (float*)(us + 2781184);
  float* Tm   = fb;                          // [208][512]
  float* Pm   = fb + 106496;                 // [200][256]
  float* Qm   = fb + 157696;                 // [200][256]
  float* Um   = fb + 208896;                 // [200][4]
  float* wp1T = fb + 209696;                 // float4[128]

  // 1) prep: transposes, conversions, P/Q
  k_prep<<<897, 256, 0, stream>>>(w1, w2, w3, wp2, we2, bbox, dir, we1, be1, roi, wp1,
                                  w1T, w2T, w3T, WrT, we2T, roiB, Pm, Qm, wp1T);

  // 2) fused node chain: h1->h2->x (LDS) -> Tm + nodevec outputs
  k_chain<<<13, 1024, 0, stream>>>(roiB, w1T, b1, w2T, b2, w3T, b3, WrT,
                                   wi, bi, rootw, rootb, bp2, out1, Um, out0, Tm);

  // 3) fused edge pipeline
  k_edge<<<622, 256, 0, stream>>>(Pm, Qm, we2T, be2, we3, be3, wp1T, bp1, pri, Tm, Um, out0, out2);
}

// Round 8
// 171.713 us; speedup vs baseline: 3.4988x; 1.4542x over previous
//
#include <hip/hip_runtime.h>
#include <math.h>

#define NN 200
#define ETOT 39800

typedef float float4v __attribute__((ext_vector_type(4)));
typedef short short8 __attribute__((ext_vector_type(8)));

__device__ __forceinline__ float sigf(float x) { return 1.0f / (1.0f + expf(-x)); }

__device__ __forceinline__ unsigned short f2b(float f) {
  unsigned u = __float_as_uint(f);
  u += 0x7fffu + ((u >> 16) & 1u);
  return (unsigned short)(u >> 16);
}
__device__ __forceinline__ float b2f16(unsigned short u) {
  return __uint_as_float(((unsigned)u) << 16);
}

// ======================= L1: everything that depends only on raw inputs =======================
// [0,416):    h1 = relu(roi@w1 + b1)  [208x512] bf16, inline transpose/convert loads
// [416,928):  G = (w3 @ Wr)^T layout [512][256] bf16   (Wr[i][j]=wp2[j>>2][4i+(j&3)])
// [928,1184): G12[c][12] = w3 row c @ [wi|rootw|bp2]   f32
// [1184,1384): P/Q per node
// [1384,1400): we2T bf16 [64][256]
// [1400,1432): w2 -> w2T bf16 [256][512]
// [1432,1440): gvec[512] = b3 @ Wr
// 1440: wp1T;  1441: bcat[12] = b3 @ [wi|rootw|bp2]
__global__ __launch_bounds__(256) void k_L1(
    const float* __restrict__ roi, const float* __restrict__ w1, const float* __restrict__ b1,
    const float* __restrict__ wp2, const float* __restrict__ w3,
    const float* __restrict__ wi, const float* __restrict__ rootw, const float* __restrict__ bp2,
    const float* __restrict__ b3, const float* __restrict__ w2, const float* __restrict__ we2,
    const float* __restrict__ bbox, const float* __restrict__ dir,
    const float* __restrict__ we1, const float* __restrict__ be1, const float* __restrict__ wp1,
    unsigned short* __restrict__ h1, unsigned short* __restrict__ Gm, float* __restrict__ G12f,
    float* __restrict__ Pm, float* __restrict__ Qm,
    unsigned short* __restrict__ we2T, unsigned short* __restrict__ w2T,
    float* __restrict__ wp1T, float* __restrict__ gvec, float* __restrict__ bcat) {
  __shared__ __align__(16) char sm[16640];
  const int b = blockIdx.x, tid = threadIdx.x;
  const int lane = tid & 63, wv = tid >> 6, mr = lane & 15, quad = lane >> 4;

  if (b < 416) {
    // ---- h1 tile: M=208 (13), N=512 (32), K=2048, inline convert ----
    const int m0 = (b % 13) * 16, n0 = (b / 13) * 16;
    const int arow = min(m0 + mr, 199);
    const float* Ap = roi + (size_t)arow * 2048 + wv * 512 + quad * 8;
    const float* Bp0 = w1 + n0 + mr;
    float4v acc = {0.f, 0.f, 0.f, 0.f};
    for (int ks = 0; ks < 16; ++ks) {
      float4v a0 = *(const float4v*)(Ap + ks * 32);
      float4v a1 = *(const float4v*)(Ap + ks * 32 + 4);
      short8 af, bf;
      af[0]=f2b(a0[0]); af[1]=f2b(a0[1]); af[2]=f2b(a0[2]); af[3]=f2b(a0[3]);
      af[4]=f2b(a1[0]); af[5]=f2b(a1[1]); af[6]=f2b(a1[2]); af[7]=f2b(a1[3]);
      const float* Bp = Bp0 + (size_t)(wv * 512 + ks * 32 + quad * 8) * 512;
#pragma unroll
      for (int t8 = 0; t8 < 8; ++t8) bf[t8] = f2b(Bp[(size_t)t8 * 512]);
      acc = __builtin_amdgcn_mfma_f32_16x16x32_bf16(af, bf, acc, 0, 0, 0);
    }
    float (*red)[16][17] = (float (*)[16][17])sm;
#pragma unroll
    for (int r = 0; r < 4; ++r) red[wv][quad * 4 + r][mr] = acc[r];
    __syncthreads();
    const int row = tid >> 4, col = tid & 15;
    float v = red[0][row][col] + red[1][row][col] + red[2][row][col] + red[3][row][col] + b1[n0 + col];
    h1[(size_t)(m0 + row) * 512 + n0 + col] = f2b(fmaxf(v, 0.f));
  } else if (b < 928) {
    // ---- G tile: M=512 (32) over j, N=256 (16) over c, K=1024 over i ----
    const int t = b - 416;
    const int j0 = (t % 32) * 16, c0 = (t / 32) * 16;
    const int j = j0 + mr;
    const float* Aw = wp2 + (size_t)(j >> 2) * 4096 + (j & 3);
    const float* Bp0 = w3 + (size_t)(c0 + mr) * 1024;
    float4v acc = {0.f, 0.f, 0.f, 0.f};
    for (int ks = 0; ks < 8; ++ks) {
      const int i0 = wv * 256 + ks * 32 + quad * 8;
      short8 af, bf;
#pragma unroll
      for (int t8 = 0; t8 < 8; ++t8) af[t8] = f2b(Aw[4 * (i0 + t8)]);
      float4v b0 = *(const float4v*)(Bp0 + i0);
      float4v b1v = *(const float4v*)(Bp0 + i0 + 4);
      bf[0]=f2b(b0[0]); bf[1]=f2b(b0[1]); bf[2]=f2b(b0[2]); bf[3]=f2b(b0[3]);
      bf[4]=f2b(b1v[0]); bf[5]=f2b(b1v[1]); bf[6]=f2b(b1v[2]); bf[7]=f2b(b1v[3]);
      acc = __builtin_amdgcn_mfma_f32_16x16x32_bf16(af, bf, acc, 0, 0, 0);
    }
    float (*red)[16][17] = (float (*)[16][17])sm;
#pragma unroll
    for (int r = 0; r < 4; ++r) red[wv][quad * 4 + r][mr] = acc[r];
    __syncthreads();
    const int row = tid >> 4, col = tid & 15;
    float v = red[0][row][col] + red[1][row][col] + red[2][row][col] + red[3][row][col];
    Gm[(size_t)(j0 + row) * 256 + c0 + col] = f2b(v);
  } else if (b < 1184) {
    // ---- G12 row c ----
    const int c = b - 928;
    float s[12] = {};
#pragma unroll
    for (int ii = 0; ii < 4; ++ii) {
      int i = tid + ii * 256;
      float xv = w3[(size_t)c * 1024 + i];
      float4v wi4 = ((const float4v*)wi)[i];
      float4v rw4 = ((const float4v*)rootw)[i];
      float4v bp4 = ((const float4v*)bp2)[i];
#pragma unroll
      for (int q = 0; q < 4; ++q) {
        s[q] += xv * wi4[q]; s[4 + q] += xv * rw4[q]; s[8 + q] += xv * bp4[q];
      }
    }
    float (*part)[12] = (float (*)[12])sm;
#pragma unroll
    for (int r = 0; r < 12; ++r) {
      float v = s[r];
#pragma unroll
      for (int off = 32; off > 0; off >>= 1) v += __shfl_down(v, off, 64);
      if (lane == 0) part[wv][r] = v;
    }
    __syncthreads();
    if (tid < 12) G12f[c * 12 + tid] = part[0][tid] + part[1][tid] + part[2][tid] + part[3][tid];
  } else if (b < 1384) {
    // ---- P/Q ----
    const int n = b - 1184, c = tid;
    float a[8];
#pragma unroll
    for (int r = 0; r < 4; ++r) a[r] = bbox[n * 4 + r] * (1.0f / 1024.0f);
#pragma unroll
    for (int r = 0; r < 4; ++r) a[4 + r] = dir[n * 4 + r];
    float p = be1[c], q = 0.0f;
#pragma unroll
    for (int r = 0; r < 8; ++r) {
      p += a[r] * we1[r * 256 + c];
      q += a[r] * we1[(8 + r) * 256 + c];
    }
    Pm[n * 256 + c] = p;
    Qm[n * 256 + c] = q;
  } else if (b < 1400) {
    // ---- we2T ----
    const int f = (b - 1384) * 256 + tid;
    const int c = f >> 6, k0 = (f & 63) * 4;
#pragma unroll
    for (int q = 0; q < 4; ++q)
      we2T[c * 256 + k0 + q] = f2b(we2[(k0 + q) * 64 + c]);
  } else if (b < 1432) {
    // ---- w2 -> w2T (LDS transpose) ----
    float (*lds)[65] = (float (*)[65])sm;
    const int t = b - 1400;
    const int kt = t % 8, nt = t / 8;
#pragma unroll 4
    for (int i = 0; i < 16; ++i) {
      int idx = tid + i * 256;
      int r = idx >> 6, c = idx & 63;
      lds[r][c] = w2[(size_t)(kt * 64 + r) * 256 + nt * 64 + c];
    }
    __syncthreads();
#pragma unroll 4
    for (int i = 0; i < 16; ++i) {
      int idx = tid + i * 256;
      int r = idx >> 6, c = idx & 63;
      w2T[(size_t)(nt * 64 + r) * 512 + kt * 64 + c] = f2b(lds[c][r]);
    }
  } else if (b < 1440) {
    // ---- gvec[j] = sum_i b3[i]*Wr[i][j] ----
    const int j = (b - 1432) * 64 + (tid >> 2), p = tid & 3;
    const float* src = wp2 + (size_t)(j >> 2) * 4096 + (j & 3);
    float v = 0.f;
    for (int t = 0; t < 256; ++t) {
      int i = p + 4 * t;
      v += b3[i] * src[4 * i];
    }
    v += __shfl_down(v, 2, 4);
    v += __shfl_down(v, 1, 4);
    if (p == 0) gvec[j] = v;
  } else if (b == 1440) {
    if (tid < 128) {
      float4v v = {wp1[tid], wp1[128 + tid], wp1[256 + tid], wp1[384 + tid]};
      ((float4v*)wp1T)[tid] = v;
    }
  } else {
    // ---- bcat ----
    float s[12] = {};
#pragma unroll
    for (int ii = 0; ii < 4; ++ii) {
      int i = tid + ii * 256;
      float xv = b3[i];
      float4v wi4 = ((const float4v*)wi)[i];
      float4v rw4 = ((const float4v*)rootw)[i];
      float4v bp4 = ((const float4v*)bp2)[i];
#pragma unroll
      for (int q = 0; q < 4; ++q) {
        s[q] += xv * wi4[q]; s[4 + q] += xv * rw4[q]; s[8 + q] += xv * bp4[q];
      }
    }
    float (*part)[12] = (float (*)[12])sm;
#pragma unroll
    for (int r = 0; r < 12; ++r) {
      float v = s[r];
#pragma unroll
      for (int off = 32; off > 0; off >>= 1) v += __shfl_down(v, off, 64);
      if (lane == 0) part[wv][r] = v;
    }
    __syncthreads();
    if (tid < 12) bcat[tid] = part[0][tid] + part[1][tid] + part[2][tid] + part[3][tid];
  }
}

// ======================= L2: h2 = relu(h1 @ w2T + b2), 208 tiles =======================
__global__ __launch_bounds__(256) void k_L2(const unsigned short* __restrict__ h1,
                                            const unsigned short* __restrict__ w2T,
                                            const float* __restrict__ b2,
                                            unsigned short* __restrict__ h2) {
  __shared__ float red[4][16][17];
  const int tid = threadIdx.x, lane = tid & 63, wv = tid >> 6;
  const int m0 = (blockIdx.x % 13) * 16, n0 = (blockIdx.x / 13) * 16;
  const int mr = lane & 15, quad = lane >> 4;
  const unsigned short* Ap = h1 + (size_t)(m0 + mr) * 512 + wv * 128 + quad * 8;
  const unsigned short* Bp = w2T + (size_t)(n0 + mr) * 512 + wv * 128 + quad * 8;
  float4v acc = {0.f, 0.f, 0.f, 0.f};
#pragma unroll
  for (int s = 0; s < 4; ++s) {
    short8 af = *(const short8*)(Ap + s * 32);
    short8 bf = *(const short8*)(Bp + s * 32);
    acc = __builtin_amdgcn_mfma_f32_16x16x32_bf16(af, bf, acc, 0, 0, 0);
  }
#pragma unroll
  for (int r = 0; r < 4; ++r) red[wv][quad * 4 + r][mr] = acc[r];
  __syncthreads();
  const int row = tid >> 4, col = tid & 15;
  float v = red[0][row][col] + red[1][row][col] + red[2][row][col] + red[3][row][col] + b2[n0 + col];
  h2[(size_t)(m0 + row) * 256 + n0 + col] = f2b(fmaxf(v, 0.f));
}

// ======================= L3: Tm = h2@G + gvec (416 tiles) | nodevec (200) =======================
__global__ __launch_bounds__(256) void k_L3(const unsigned short* __restrict__ h2,
                                            const unsigned short* __restrict__ Gm,
                                            const float* __restrict__ gvec,
                                            const float* __restrict__ G12f, const float* __restrict__ bcat,
                                            const float* __restrict__ bi, const float* __restrict__ rootb,
                                            float* __restrict__ Tm, float* __restrict__ out1,
                                            float* __restrict__ Um, float* __restrict__ out0) {
  __shared__ __align__(16) char sm[4352];
  const int b = blockIdx.x, tid = threadIdx.x;
  const int lane = tid & 63, wv = tid >> 6, mr = lane & 15, quad = lane >> 4;
  if (b < 416) {
    float (*red)[16][17] = (float (*)[16][17])sm;
    const int m0 = (b % 13) * 16, n0 = (b / 13) * 16;
    const unsigned short* Ap = h2 + (size_t)(m0 + mr) * 256 + wv * 64 + quad * 8;
    const unsigned short* Bp = Gm + (size_t)(n0 + mr) * 256 + wv * 64 + quad * 8;
    float4v acc = {0.f, 0.f, 0.f, 0.f};
#pragma unroll
    for (int s = 0; s < 2; ++s) {
      short8 af = *(const short8*)(Ap + s * 32);
      short8 bf = *(const short8*)(Bp + s * 32);
      acc = __builtin_amdgcn_mfma_f32_16x16x32_bf16(af, bf, acc, 0, 0, 0);
    }
#pragma unroll
    for (int r = 0; r < 4; ++r) red[wv][quad * 4 + r][mr] = acc[r];
    __syncthreads();
    const int row = tid >> 4, col = tid & 15;
    float v = red[0][row][col] + red[1][row][col] + red[2][row][col] + red[3][row][col] + gvec[n0 + col];
    Tm[(size_t)(m0 + row) * 512 + n0 + col] = v;
  } else {
    // nodevec from h2
    const int n = b - 416;
    const float xv = b2f16(h2[(size_t)n * 256 + tid]);
    const float4v* g4 = (const float4v*)(G12f + tid * 12);
    float s[12];
    float4v v0 = g4[0], v1 = g4[1], v2 = g4[2];
    s[0]=xv*v0[0]; s[1]=xv*v0[1]; s[2]=xv*v0[2]; s[3]=xv*v0[3];
    s[4]=xv*v1[0]; s[5]=xv*v1[1]; s[6]=xv*v1[2]; s[7]=xv*v1[3];
    s[8]=xv*v2[0]; s[9]=xv*v2[1]; s[10]=xv*v2[2]; s[11]=xv*v2[3];
    float (*part)[12] = (float (*)[12])sm;
#pragma unroll
    for (int r = 0; r < 12; ++r) {
      float v = s[r];
#pragma unroll
      for (int off = 32; off > 0; off >>= 1) v += __shfl_down(v, off, 64);
      if (lane == 0) part[wv][r] = v;
    }
    __syncthreads();
    if (tid < 12) {
      float v = part[0][tid] + part[1][tid] + part[2][tid] + part[3][tid] + bcat[tid];
      int kind = tid >> 2, c = tid & 3;
      if (kind == 0) out1[n * 4 + c] = sigf(v + bi[c]);
      else if (kind == 1) out0[n * 4 + c] = v + rootb[c];
      else Um[n * 4 + c] = v;
    }
  }
}

// ======================= L4: fused edge kernel (unchanged from round 7) =======================
__global__ __launch_bounds__(256) void k_edge(
    const float* __restrict__ P, const float* __restrict__ Q,
    const unsigned short* __restrict__ we2T,
    const float* __restrict__ be2, const float* __restrict__ we3, const float* __restrict__ be3,
    const float* __restrict__ wp1T, const float* __restrict__ bp1,
    const float* __restrict__ pri,
    const float* __restrict__ T, const float* __restrict__ U,
    float* __restrict__ out0, float* __restrict__ out_ea) {
  __shared__ int src_s[64], dst_s[64];
  __shared__ float ea_s[64][4];
  __shared__ float4v wp1s[128];
  __shared__ float bp1s[128];
  __shared__ float4v Ts[2][128];
  __shared__ float Us[2][4];

  const int tid = threadIdx.x;
  const int e0 = blockIdx.x * 64;
  const int s_lo = e0 / 199;

  if (tid < 64) {
    int e = e0 + tid;
    int i = -1, j = 0;
    if (e < ETOT) {
      i = e / 199;
      int jj = e - i * 199;
      j = jj + (jj >= i ? 1 : 0);
    }
    src_s[tid] = i;
    dst_s[tid] = j;
  }
  if (tid < 128) {
    wp1s[tid] = ((const float4v*)wp1T)[tid];
    bp1s[tid] = bp1[tid];
  }
  {
    int row = tid >> 7, c = tid & 127;
    Ts[row][c] = ((const float4v*)T)[(s_lo + row) * 128 + c];
  }
  if (tid < 8) {
    int s = min(s_lo + (tid >> 2), 199);
    Us[tid >> 2][tid & 3] = U[s * 4 + (tid & 3)];
  }
  __syncthreads();

  const int lane = tid & 63;
  const int wv = tid >> 6;
  const int m = lane & 15;
  const int quad = lane >> 4;
  const int eloc = wv * 16 + m;
  const int si = src_s[eloc];
  const int dj = dst_s[eloc];

  float4v acc[4];
#pragma unroll
  for (int ct = 0; ct < 4; ++ct) { acc[ct][0] = 0.f; acc[ct][1] = 0.f; acc[ct][2] = 0.f; acc[ct][3] = 0.f; }

  const short8* W8 = (const short8*)we2T;

  for (int ks = 0; ks < 8; ++ks) {
    union { short8 s; unsigned u[4]; } af;
    af.s = (short8)0;
    if (si >= 0) {
      const float4v* p4 = (const float4v*)(P + si * 256 + ks * 32 + quad * 8);
      const float4v* q4 = (const float4v*)(Q + dj * 256 + ks * 32 + quad * 8);
      float4v v0 = p4[0] + q4[0];
      float4v v1 = p4[1] + q4[1];
      af.u[0] = (unsigned)f2b(fmaxf(v0[0], 0.f)) | ((unsigned)f2b(fmaxf(v0[1], 0.f)) << 16);
      af.u[1] = (unsigned)f2b(fmaxf(v0[2], 0.f)) | ((unsigned)f2b(fmaxf(v0[3], 0.f)) << 16);
      af.u[2] = (unsigned)f2b(fmaxf(v1[0], 0.f)) | ((unsigned)f2b(fmaxf(v1[1], 0.f)) << 16);
      af.u[3] = (unsigned)f2b(fmaxf(v1[2], 0.f)) | ((unsigned)f2b(fmaxf(v1[3], 0.f)) << 16);
    }
#pragma unroll
    for (int ct = 0; ct < 4; ++ct) {
      short8 bf = W8[(ct * 16 + m) * 32 + ks * 4 + quad];
      acc[ct] = __builtin_amdgcn_mfma_f32_16x16x32_bf16(af.s, bf, acc[ct], 0, 0, 0);
    }
  }

  float ev[4][3];
#pragma unroll
  for (int r = 0; r < 4; ++r) { ev[r][0] = 0.f; ev[r][1] = 0.f; ev[r][2] = 0.f; }
#pragma unroll
  for (int ct = 0; ct < 4; ++ct) {
    const int col = ct * 16 + m;
    const float b2v = be2[col];
    const float w0 = we3[col * 3 + 0], w1v = we3[col * 3 + 1], w2v = we3[col * 3 + 2];
#pragma unroll
    for (int r = 0; r < 4; ++r) {
      float e2 = fmaxf(acc[ct][r] + b2v, 0.f);
      ev[r][0] += e2 * w0;
      ev[r][1] += e2 * w1v;
      ev[r][2] += e2 * w2v;
    }
  }
#pragma unroll
  for (int r = 0; r < 4; ++r)
#pragma unroll
    for (int p = 0; p < 3; ++p) {
      float v = ev[r][p];
      v += __shfl_xor(v, 1, 64);
      v += __shfl_xor(v, 2, 64);
      v += __shfl_xor(v, 4, 64);
      v += __shfl_xor(v, 8, 64);
      ev[r][p] = v;
    }
  if (m == 0) {
#pragma unroll
    for (int r = 0; r < 4; ++r) {
      int el = wv * 16 + quad * 4 + r;
      int ss = src_s[el], dd = dst_s[el];
      if (ss >= 0) {
        float4v o;
        o[0] = sigf(ev[r][0] + be3[0]);
        o[1] = sigf(ev[r][1] + be3[1]);
        o[2] = sigf(ev[r][2] + be3[2]);
        o[3] = (pri[ss] > pri[dd]) ? 1.0f : 0.0f;
        *(float4v*)&ea_s[el][0] = o;
        *(float4v*)(out_ea + (size_t)(e0 + el) * 4) = o;
      }
    }
  }
  __syncthreads();

  const int ee = tid >> 2, pp = tid & 3;
  const int s2 = src_s[ee], d2 = dst_s[ee];
  float4v pm = {0.f, 0.f, 0.f, 0.f};
  if (s2 >= 0) {
    const int srow = s2 - s_lo;
    const float c0 = ea_s[ee][0], c1 = ea_s[ee][1], c2 = ea_s[ee][2], c3 = ea_s[ee][3];
#pragma unroll 8
    for (int tt = pp; tt < 128; tt += 4) {
      float4v w4 = wp1s[tt];
      float hv = bp1s[tt] + c0 * w4[0] + c1 * w4[1] + c2 * w4[2] + c3 * w4[3];
      hv = fmaxf(hv, 0.f);
      pm += hv * Ts[srow][tt];
    }
  }
#pragma unroll
  for (int o = 0; o < 4; ++o) {
    float v = pm[o];
    v += __shfl_xor(v, 1, 64);
    v += __shfl_xor(v, 2, 64);
    pm[o] = v;
  }
  if (s2 >= 0) atomicAdd(&out0[d2 * 4 + pp], Us[s2 - s_lo][pp] + pm[pp]);
}

extern "C" void kernel_launch(void* const* d_in, const int* in_sizes, int n_in,
                              void* d_out, int out_size, void* d_ws, size_t ws_size,
                              hipStream_t stream) {
  (void)in_sizes; (void)n_in; (void)out_size; (void)ws_size;
  const float* roi   = (const float*)d_in[0];
  const float* bbox  = (const float*)d_in[1];
  const float* dir   = (const float*)d_in[2];
  const float* pri   = (const float*)d_in[3];
  const float* w1    = (const float*)d_in[4];
  const float* b1    = (const float*)d_in[5];
  const float* w2    = (const float*)d_in[6];
  const float* b2    = (const float*)d_in[7];
  const float* w3    = (const float*)d_in[8];
  const float* b3    = (const float*)d_in[9];
  const float* wi    = (const float*)d_in[10];
  const float* bi    = (const float*)d_in[11];
  const float* we1   = (const float*)d_in[12];
  const float* be1   = (const float*)d_in[13];
  const float* we2   = (const float*)d_in[14];
  const float* be2   = (const float*)d_in[15];
  const float* we3   = (const float*)d_in[16];
  const float* be3   = (const float*)d_in[17];
  const float* wp1   = (const float*)d_in[18];
  const float* bp1   = (const float*)d_in[19];
  const float* wp2   = (const float*)d_in[20];
  const float* bp2   = (const float*)d_in[21];
  const float* rootw = (const float*)d_in[22];
  const float* rootb = (const float*)d_in[23];

  float* out0 = (float*)d_out;        // next_actions [200,4]
  float* out1 = out0 + 800;           // node_concepts_explicit[0] [200,4]
  float* out2 = out0 + 1600;          // edge_attributes[0] [39800,4]

  // ---- workspace ----
  unsigned short* us = (unsigned short*)d_ws;
  unsigned short* h1   = us;                 // [208][512] bf16
  unsigned short* h2   = us + 106496;        // [208][256] bf16
  unsigned short* Gm   = us + 159744;        // [512][256] bf16
  unsigned short* we2T = us + 290816;        // [64][256] bf16
  unsigned short* w2T  = us + 307200;        // [256][512] bf16
  float* fb   = (float*)(us + 438272);
  float* Tm   = fb;                          // [208][512] f32
  float* Pm   = fb + 106496;                 // [200][256]
  float* Qm   = fb + 157696;                 // [200][256]
  float* Um   = fb + 208896;                 // [200][4]
  float* wp1T = fb + 209696;                 // float4[128]
  float* G12f = fb + 210208;                 // [256][12]
  float* gvec = fb + 213280;                 // [512]
  float* bcat = fb + 213792;                 // [12]

  k_L1<<<1442, 256, 0, stream>>>(roi, w1, b1, wp2, w3, wi, rootw, bp2, b3, w2, we2,
                                 bbox, dir, we1, be1, wp1,
                                 h1, Gm, G12f, Pm, Qm, we2T, w2T, wp1T, gvec, bcat);

  k_L2<<<208, 256, 0, stream>>>(h1, w2T, b2, h2);

  k_L3<<<616, 256, 0, stream>>>(h2, Gm, gvec, G12f, bcat, bi, rootb, Tm, out1, Um, out0);

  k_edge<<<622, 256, 0, stream>>>(Pm, Qm, we2T, be2, we3, be3, wp1T, bp1, pri, Tm, Um, out0, out2);
}